// Round 1
// 181.233 us; speedup vs baseline: 1.0544x; 1.0544x over previous
//
#include <hip/hip_runtime.h>
#include <hip/hip_bf16.h>

// Problem constants
#define BB 2
#define SS 2048
#define HH 1024
#define NHH 16
#define HDD 64
#define MM (BB*SS)        // 4096
#define QKV_N (3*HH)      // 3072

typedef _Float16 f16x8 __attribute__((ext_vector_type(8)));
typedef _Float16 f16x4 __attribute__((ext_vector_type(4)));
typedef float f32x4 __attribute__((ext_vector_type(4)));

#define MFMA16(a,b,c)  __builtin_amdgcn_mfma_f32_16x16x32_f16((a),(b),(c),0,0,0)
#define MFMA16K16(a,b,c) __builtin_amdgcn_mfma_f32_16x16x16f16((a),(b),(c),0,0,0)

// async global->LDS 16B per lane; LDS dest = wave-uniform base + lane*16
__device__ __forceinline__ void gl2lds16(const _Float16* g, _Float16* l) {
    __builtin_amdgcn_global_load_lds(
        (const __attribute__((address_space(1))) void*)g,
        (__attribute__((address_space(3))) void*)l, 16, 0, 0);
}

// single-instruction exp2 WITH compiler hazard handling (raw asm broke TRANS-op waits)
__device__ __forceinline__ float fexp2(float x) { return __builtin_amdgcn_exp2f(x); }

// ---------------- prep: z<4 transpose-cast W -> Wt fp16; z==4 cast X -> fp16 ------------
// grid (16,16,5), block 256.
__global__ __launch_bounds__(256) void prep_kernel(
    const float* __restrict__ X,
    const float* __restrict__ W0, const float* __restrict__ W1,
    const float* __restrict__ W2, const float* __restrict__ W3,
    _Float16* __restrict__ Xh,
    _Float16* __restrict__ WqkvT, _Float16* __restrict__ WoT)
{
    __shared__ float t[64][65];
    int z = blockIdx.z;
    int tid = threadIdx.x;
    if (z == 4) {
        int base = (blockIdx.y * 16 + blockIdx.x) * 256 + tid;
        const float4* xin = (const float4*)X;
        f16x4* xout = (f16x4*)Xh;
#pragma unroll
        for (int i = 0; i < 16; ++i) {
            float4 v = xin[base + i * 65536];
            f16x4 hh = {(_Float16)v.x, (_Float16)v.y, (_Float16)v.z, (_Float16)v.w};
            xout[base + i * 65536] = hh;
        }
        return;
    }
    const float* src = (z == 0) ? W0 : (z == 1) ? W1 : (z == 2) ? W2 : W3;
    _Float16* dst = (z < 3) ? (WqkvT + (size_t)z * HH * HH) : WoT;
    int k0 = blockIdx.y * 64, n0 = blockIdx.x * 64;
#pragma unroll
    for (int p = 0; p < 4; ++p) {
        int row = p * 16 + (tid >> 4);
        int col4 = (tid & 15) * 4;
        float4 v = *(const float4*)&src[(size_t)(k0 + row) * HH + n0 + col4];
        t[row][col4 + 0] = v.x; t[row][col4 + 1] = v.y;
        t[row][col4 + 2] = v.z; t[row][col4 + 3] = v.w;
    }
    __syncthreads();
#pragma unroll
    for (int p = 0; p < 2; ++p) {
        int nc = p * 32 + (tid >> 3);
        int ch = tid & 7;
        f16x8 o;
#pragma unroll
        for (int j = 0; j < 8; ++j) o[j] = (_Float16)t[ch * 8 + j][nc];
        *(f16x8*)&dst[(size_t)(n0 + nc) * HH + k0 + ch * 8] = o;
    }
}

// ---------------- MFMA GEMM 128x128 tile, 3-stage pipeline, raw barrier ----------------
template<int MODE>
__global__ __launch_bounds__(256) void gemm128_kernel(
    const _Float16* __restrict__ A, const _Float16* __restrict__ Bt,
    const float* __restrict__ bias0, const float* __restrict__ bias1, const float* __restrict__ bias2,
    _Float16* __restrict__ Qh, _Float16* __restrict__ Kh, _Float16* __restrict__ Vt,
    float* __restrict__ Out)
{
    const int K = HH;
    const int NT = K / 32;
    __shared__ _Float16 smem[24576];          // 49152 B: 3-stage bufs U epilogue tile 128x132

    int row0 = blockIdx.y * 128, n0 = blockIdx.x * 128;
    int tid = threadIdx.x;
    int w = tid >> 6, l = tid & 63, m16 = l & 15, quad = l >> 4;
    int wm = w >> 1, wn = w & 1;

    int srow = w * 32 + (l >> 2);
    int sch = (l & 3) ^ ((l >> 2) & 3) ^ ((l >> 4) & 3);
    const _Float16* aptr = A + (size_t)(row0 + srow) * K + sch * 8;
    const _Float16* bptr = Bt + (size_t)(n0 + srow) * K + sch * 8;

    int gsw = (m16 & 3) ^ ((m16 >> 2) & 3);
    int acol = (quad ^ gsw) * 8;

    f32x4 zero4 = {0.f, 0.f, 0.f, 0.f};
    f32x4 acc[4][4];
#pragma unroll
    for (int i = 0; i < 4; ++i)
#pragma unroll
        for (int j = 0; j < 4; ++j) acc[i][j] = zero4;

    auto stage = [&](int t, int s) {
        int k0 = t * 32;
        int ao = s * 4096 + (w * 32) * 32;
        int bo = 12288 + s * 4096 + (w * 32) * 32;
        gl2lds16(aptr + k0, smem + ao);
        gl2lds16(aptr + (size_t)16 * K + k0, smem + ao + 16 * 32);
        gl2lds16(bptr + k0, smem + bo);
        gl2lds16(bptr + (size_t)16 * K + k0, smem + bo + 16 * 32);
    };

    stage(0, 0);
    stage(1, 1);
    int cur = 0;
    for (int t = 0; t < NT; ++t) {
        if (t < NT - 1) asm volatile("s_waitcnt vmcnt(4)" ::: "memory");
        else            asm volatile("s_waitcnt vmcnt(0)" ::: "memory");
        asm volatile("s_barrier" ::: "memory");
        if (t + 2 < NT) {
            int nxt = cur + 2; if (nxt >= 3) nxt -= 3;
            stage(t + 2, nxt);
        }
        const _Float16* Asr = smem + cur * 4096;
        const _Float16* Bsr = smem + 12288 + cur * 4096;
        f16x8 af[4], bf[4];
#pragma unroll
        for (int i = 0; i < 4; ++i)
            af[i] = *(const f16x8*)&Asr[(wm * 64 + i * 16 + m16) * 32 + acol];
#pragma unroll
        for (int j = 0; j < 4; ++j)
            bf[j] = *(const f16x8*)&Bsr[(wn * 64 + j * 16 + m16) * 32 + acol];
#pragma unroll
        for (int i = 0; i < 4; ++i)
#pragma unroll
            for (int j = 0; j < 4; ++j)
                acc[i][j] = MFMA16(af[i], bf[j], acc[i][j]);
        cur = (cur == 2) ? 0 : cur + 1;
    }

    if (MODE == 1) {
#pragma unroll
        for (int j = 0; j < 4; ++j) {
            int n = n0 + wn * 64 + j * 16 + m16;
            float bi = bias0[n];
#pragma unroll
            for (int i = 0; i < 4; ++i)
#pragma unroll
                for (int r = 0; r < 4; ++r) {
                    int mg = row0 + wm * 64 + i * 16 + quad * 4 + r;
                    Out[(size_t)mg * HH + n] = acc[i][j][r] + bi;
                }
        }
        return;
    }

    // ---- MODE 0 epilogue: bias (+scale for Q), LDS bounce, coalesced stores ----
    int which = n0 >> 10;                     // 0=Q 1=K 2=V (block is pure)
    const float* bias = (which == 0) ? bias0 : (which == 1) ? bias1 : bias2;
    __syncthreads();
#pragma unroll
    for (int j = 0; j < 4; ++j) {
        int n_local = wn * 64 + j * 16 + m16;
        float bi = bias[(n0 + n_local) & 1023];
#pragma unroll
        for (int i = 0; i < 4; ++i)
#pragma unroll
            for (int r = 0; r < 4; ++r) {
                int m_local = wm * 64 + i * 16 + quad * 4 + r;
                float v = acc[i][j][r] + bi;
                if (which == 0) v *= 0.18033688011112042f;  // (1/sqrt(64))*log2(e)
                if (which == 2) smem[n_local * 132 + m_local] = (_Float16)v;   // transposed
                else            smem[m_local * 132 + n_local] = (_Float16)v;
            }
    }
    __syncthreads();

    int b = row0 >> 11, s0 = row0 & 2047;
    if (which == 2) {
#pragma unroll
        for (int p = 0; p < 8; ++p) {
            int n_local = p * 16 + (tid >> 4);
            int schunk = tid & 15;
            f16x8 v = *(const f16x8*)&smem[n_local * 132 + schunk * 8];
            int nw = (n0 + n_local) & 1023;
            int hh = nw >> 6, d = nw & 63;
            *(f16x8*)&Vt[((size_t)(b * NHH + hh) * HDD + d) * SS + s0 + schunk * 8] = v;
        }
    } else {
        _Float16* dst = (which == 0) ? Qh : Kh;
        int hh0 = (n0 & 1023) >> 6;
#pragma unroll
        for (int p = 0; p < 8; ++p) {
            int m_local = p * 16 + (tid >> 4);
            int seg = tid & 15;
            f16x8 v = *(const f16x8*)&smem[m_local * 132 + seg * 8];
            int hh = hh0 + (seg >> 3), d = (seg & 7) * 8;
            *(f16x8*)&dst[((size_t)(b * NHH + hh) * SS + s0 + m_local) * HDD + d] = v;
        }
    }
}

// ---------------- Flash attention: S^T formulation, 8-wave tile-split --------------
// grid (16, NH, B), block 512 (8 waves). Waves 0-3 own q-tile tA=bx (16 rows each),
// waves 4-7 own q-tile tB=31-tA. Pairing balances work (tA+tB+2 = 33 bodies/block-4waves).
// vs previous 4-wave version: same grid, 2x waves/SIMD (2->4) to hide the serial
// QK-MFMA -> exp2 -> PV-MFMA chain + barrier/vmcnt latency (occupancy was 15.7%,
// both MfmaUtil and VALUBusy < 25% => latency-bound).
// Staging: 8 waves x 8 rows x (K,V), one gl2lds16 per matrix per wave (vmcnt counts 4->2).
// Inactive waves (A-waves past tA) skip frag reads + body but keep staging/barriers.
__global__ __launch_bounds__(512, 4) void attn_kernel(
    const _Float16* __restrict__ Qh, const _Float16* __restrict__ Kh,
    const _Float16* __restrict__ Vt, _Float16* __restrict__ Ctx)
{
    __shared__ _Float16 KV[3 * 8192];     // 49152 B, 3-stage K+V

    int tid = threadIdx.x;
    int w = tid >> 6, l = tid & 63;
    int m16 = l & 15, quad = l >> 4;
    int b = blockIdx.z, h = blockIdx.y;
    int tA = blockIdx.x, tB = 31 - tA;
    int half = w >> 2, wq = w & 3;
    int myT = half ? tB : tA;             // this wave's q-tile index

    const _Float16* Q = Qh + (size_t)(b * NHH + h) * SS * HDD;
    const _Float16* K = Kh + (size_t)(b * NHH + h) * SS * HDD;
    const _Float16* V = Vt + (size_t)(b * NHH + h) * HDD * SS;

    int q = myT * 64 + wq * 16 + m16;     // this lane's q row (S^T: q = lane&15)
    f16x8 aq0 = *(const f16x8*)(Q + (size_t)q * HDD + quad * 8);
    f16x8 aq1 = *(const f16x8*)(Q + (size_t)q * HDD + 32 + quad * 8);

    // staging: wave w covers rows [w*8, w*8+8), one 8-row instr per matrix
    int srow = w * 8 + (l >> 3);
    int sch = (l & 7) ^ (l >> 3);         // row&7 == (l>>3)&7 since w*8 is 8-aligned
    const _Float16* kg = K + (size_t)srow * HDD + sch * 8;
    const _Float16* vg = V + (size_t)srow * SS + sch * 8;

    auto stage = [&](int t, int s) {
        int kt = t * 64;
        _Float16* kb = &KV[s * 8192];
        _Float16* vb = &KV[s * 8192 + 4096];
        gl2lds16(kg + (size_t)kt * HDD, kb + (w * 8) * 64);
        gl2lds16(vg + kt, vb + (w * 8) * 64);
    };

    int swz = m16 & 7;
    int cka = (quad ^ swz) * 8;          // K-frag d-chunk 0..31
    int ckb = ((quad + 4) ^ swz) * 8;    // K-frag d-chunk 32..63
    int vco[4];
#pragma unroll
    for (int s = 0; s < 4; ++s)
        vco[s] = (((s * 2 + (quad >> 1)) ^ swz) * 8) + (quad & 1) * 4;

    f32x4 zero4 = {0.f, 0.f, 0.f, 0.f};
    const f16x4 ones4 = {(_Float16)1.f, (_Float16)1.f, (_Float16)1.f, (_Float16)1.f};
    f32x4 o[4];                          // O^T: row d=c*16+quad*4+r, col q=m16
#pragma unroll
    for (int c = 0; c < 4; ++c) o[c] = zero4;
    f32x4 lacc = zero4;                  // softmax denominator (all rows identical)

    stage(0, 0);
    stage(1, 1);
    int cur = 0;
    for (int t = 0; t <= tB; ++t) {
        int kt = t * 64;
        if (t < tB) asm volatile("s_waitcnt vmcnt(2)" ::: "memory");
        else        asm volatile("s_waitcnt vmcnt(0)" ::: "memory");
        asm volatile("s_barrier" ::: "memory");
        if (t + 2 <= tB) {
            int nxt = cur + 2; if (nxt >= 3) nxt -= 3;
            stage(t + 2, nxt);
        }

        if (t <= myT) {                   // wave-uniform: body only while tile active
            const _Float16* kb = &KV[cur * 8192];
            const _Float16* vb = &KV[cur * 8192 + 4096];
            f16x8 bk[4][2];
#pragma unroll
            for (int s = 0; s < 4; ++s) {
                const _Float16* kr = kb + (s * 16 + m16) * 64;
                bk[s][0] = *(const f16x8*)(kr + cka);
                bk[s][1] = *(const f16x8*)(kr + ckb);
            }
            f16x4 av[4][4];              // [c d-block][s key-chunk]
#pragma unroll
            for (int c = 0; c < 4; ++c) {
                const _Float16* vr = vb + (c * 16 + m16) * 64;
#pragma unroll
                for (int s = 0; s < 4; ++s)
                    av[c][s] = *(const f16x4*)(vr + vco[s]);
            }

            f32x4 st[4];
#pragma unroll
            for (int s = 0; s < 4; ++s) {
                st[s] = MFMA16(bk[s][0], aq0, zero4);
                st[s] = MFMA16(bk[s][1], aq1, st[s]);
            }
            f16x4 pt[4];
            if (t == myT) {              // masked (diagonal) tile
#pragma unroll
                for (int s = 0; s < 4; ++s)
#pragma unroll
                    for (int r = 0; r < 4; ++r) {
                        float p = fexp2(st[s][r]);
                        int key = kt + s * 16 + quad * 4 + r;
                        if (key > q) p = 0.f;
                        pt[s][r] = (_Float16)p;
                    }
            } else {
#pragma unroll
                for (int s = 0; s < 4; ++s)
#pragma unroll
                    for (int r = 0; r < 4; ++r)
                        pt[s][r] = (_Float16)fexp2(st[s][r]);
            }
#pragma unroll
            for (int s = 0; s < 4; ++s)
                lacc = MFMA16K16(ones4, pt[s], lacc);
#pragma unroll
            for (int c = 0; c < 4; ++c)
#pragma unroll
                for (int s = 0; s < 4; ++s)
                    o[c] = MFMA16K16(av[c][s], pt[s], o[c]);
        }

        cur = (cur == 2) ? 0 : cur + 1;
    }

    // epilogue: normalize (denominator identical across rows/quads for a given q), store O^T
    float inv = 1.0f / lacc[0];
    size_t rowoff = ((size_t)(b * SS) + q) * HH + h * HDD;
#pragma unroll
    for (int c = 0; c < 4; ++c) {
        f16x4 ov;
#pragma unroll
        for (int r = 0; r < 4; ++r) ov[r] = (_Float16)(o[c][r] * inv);
        *(f16x4*)&Ctx[rowoff + c * 16 + quad * 4] = ov;
    }
}

extern "C" void kernel_launch(void* const* d_in, const int* in_sizes, int n_in,
                              void* d_out, int out_size, void* d_ws, size_t ws_size,
                              hipStream_t stream) {
    const float* hs = (const float*)d_in[0];
    const float* Wq = (const float*)d_in[1];
    const float* bq = (const float*)d_in[2];
    const float* Wk = (const float*)d_in[3];
    const float* bk = (const float*)d_in[4];
    const float* Wv = (const float*)d_in[5];
    const float* bv = (const float*)d_in[6];
    const float* Wo = (const float*)d_in[7];
    const float* bo = (const float*)d_in[8];
    float* out = (float*)d_out;

    size_t off = 0;
    auto alloc = [&](size_t bytes) {
        void* p = (char*)d_ws + off;
        off += (bytes + 255) & ~(size_t)255;
        return p;
    };
    _Float16* Xh    = (_Float16*)alloc((size_t)MM * HH * 2);
    _Float16* WqkvT = (_Float16*)alloc((size_t)3 * HH * HH * 2);
    _Float16* WoT   = (_Float16*)alloc((size_t)HH * HH * 2);
    _Float16* Qh    = (_Float16*)alloc((size_t)BB * NHH * SS * HDD * 2);
    _Float16* Kh    = (_Float16*)alloc((size_t)BB * NHH * SS * HDD * 2);
    _Float16* Vt    = (_Float16*)alloc((size_t)BB * NHH * SS * HDD * 2);
    _Float16* Ctx   = (_Float16*)alloc((size_t)MM * HH * 2);

    prep_kernel<<<dim3(16, 16, 5), 256, 0, stream>>>(
        hs, Wq, Wk, Wv, Wo, Xh, WqkvT, WoT);
    gemm128_kernel<0><<<dim3(QKV_N / 128, MM / 128), 256, 0, stream>>>(
        Xh, WqkvT, bq, bk, bv, Qh, Kh, Vt, nullptr);
    attn_kernel<<<dim3(16, NHH, BB), 512, 0, stream>>>(Qh, Kh, Vt, Ctx);
    gemm128_kernel<1><<<dim3(HH / 128, MM / 128), 256, 0, stream>>>(
        Ctx, WoT, bo, bo, bo, nullptr, nullptr, nullptr, out);
}